// Round 5
// baseline (613.893 us; speedup 1.0000x reference)
//
#include <hip/hip_runtime.h>
#include <cstdint>

#define TSTEPS  128
#define INDIM   256
#define HIDDEN  64
#define FREQN   10
#define NOUT    16
#define XSTRIDE 272   // xproj cols: [i:0][ste:64][c:128][o:192][fre:256..265][pad..271]
#define NTILE   17    // 272/16 N-tiles

typedef __attribute__((ext_vector_type(8))) short bf16x8;
typedef __attribute__((ext_vector_type(4))) float f32x4;

__device__ __forceinline__ unsigned short bf16h(float x) {
    unsigned u = __float_as_uint(x);
    return (unsigned short)((u + 0x7FFFu + ((u >> 16) & 1u)) >> 16);
}
__device__ __forceinline__ float rdlane(float v, int l) {
    return __int_as_float(__builtin_amdgcn_readlane(__float_as_int(v), l));
}
__device__ __forceinline__ float hsig(float x) {
    return fminf(fmaxf(__fmaf_rn(x, (1.0f / 6.0f), 0.5f), 0.0f), 1.0f);
}
__device__ __forceinline__ float tanh_f(float x) {
    float e = __expf(2.0f * x);
    return 1.0f - 2.0f / (e + 1.0f);
}

// ---------------------------------------------------------------------------
// Pack W = [Wi|Wst|Wc|Wo|Wfre|0pad] (256 x 272) into split-bf16 MFMA B-frags.
// ---------------------------------------------------------------------------
__global__ void pack_w(const float* __restrict__ Wi, const float* __restrict__ Wst,
                       const float* __restrict__ Wc, const float* __restrict__ Wo,
                       const float* __restrict__ Wfr,
                       const float* __restrict__ bi, const float* __restrict__ bst,
                       const float* __restrict__ bc, const float* __restrict__ bo,
                       const float* __restrict__ bfr,
                       unsigned short* __restrict__ Wpk, float* __restrict__ bias)
{
    int idx = blockIdx.x * 256 + threadIdx.x;
    if (idx < 8 * NTILE * 64) {
        int l = idx & 63;
        int t = (idx >> 6) % NTILE;
        int s = idx / (64 * NTILE);
        int n = t * 16 + (l & 15);
        unsigned short* dst = Wpk + (size_t)idx * 16;
        #pragma unroll
        for (int i = 0; i < 8; ++i) {
            int k = s * 32 + (l >> 4) * 8 + i;
            float v;
            if      (n < 64)  v = Wi [k * 64 + n];
            else if (n < 128) v = Wst[k * 64 + (n - 64)];
            else if (n < 192) v = Wc [k * 64 + (n - 128)];
            else if (n < 256) v = Wo [k * 64 + (n - 192)];
            else if (n < 266) v = Wfr[k * 10 + (n - 256)];
            else              v = 0.f;
            unsigned short h = bf16h(v);
            float hf = __uint_as_float((unsigned)h << 16);
            dst[i]     = h;
            dst[8 + i] = bf16h(v - hf);
        }
    } else if (idx < 8 * NTILE * 64 + XSTRIDE) {
        int n = idx - 8 * NTILE * 64;
        float b;
        if      (n < 64)  b = bi [n];
        else if (n < 128) b = bst[n - 64];
        else if (n < 192) b = bc [n - 128];
        else if (n < 256) b = bo [n - 192];
        else if (n < 266) b = bfr[n - 256];
        else              b = 0.f;
        bias[n] = b;
    }
}

// ---------------------------------------------------------------------------
// Split-bf16 MFMA GEMM: xproj = g1 @ [W...] + bias. (unchanged from R4)
// ---------------------------------------------------------------------------
__global__ __launch_bounds__(256, 2)
void gemm_mfma(const float* __restrict__ A, const unsigned short* __restrict__ Wpk,
               const float* __restrict__ bias, float* __restrict__ outp,
               int ci, int tclog)
{
    const int tid = threadIdx.x;
    const int w   = tid >> 6, l = tid & 63;
    const int l15 = l & 15,  lg = l >> 4;
    const int tcm = (1 << tclog) - 1;
    const int rbase = blockIdx.x * 128 + w * 32;

    f32x4 acc[2][NTILE];
    #pragma unroll
    for (int rt = 0; rt < 2; ++rt)
        #pragma unroll
        for (int t = 0; t < NTILE; ++t) acc[rt][t] = (f32x4){0.f, 0.f, 0.f, 0.f};

    #pragma unroll
    for (int s = 0; s < 8; ++s) {
        bf16x8 ahi[2], alo[2];
        #pragma unroll
        for (int rt = 0; rt < 2; ++rt) {
            int rp   = rbase + rt * 16 + l15;
            int grow = ((rp >> tclog) << 7) + (ci << tclog) + (rp & tcm);
            const float* ap = A + (size_t)grow * INDIM + s * 32 + lg * 8;
            float4 a0 = *reinterpret_cast<const float4*>(ap);
            float4 a1 = *reinterpret_cast<const float4*>(ap + 4);
            float av[8] = {a0.x, a0.y, a0.z, a0.w, a1.x, a1.y, a1.z, a1.w};
            union { bf16x8 v; unsigned short u[8]; } H, L;
            #pragma unroll
            for (int i = 0; i < 8; ++i) {
                unsigned short h = bf16h(av[i]);
                H.u[i] = h;
                L.u[i] = bf16h(av[i] - __uint_as_float((unsigned)h << 16));
            }
            ahi[rt] = H.v; alo[rt] = L.v;
        }
        #pragma unroll
        for (int t = 0; t < NTILE; ++t) {
            const bf16x8* bp =
                reinterpret_cast<const bf16x8*>(Wpk + ((size_t)(s * NTILE + t) * 64 + l) * 16);
            bf16x8 bhi = bp[0], blo = bp[1];
            #pragma unroll
            for (int rt = 0; rt < 2; ++rt) {
                acc[rt][t] = __builtin_amdgcn_mfma_f32_16x16x32_bf16(ahi[rt], bhi, acc[rt][t], 0, 0, 0);
                acc[rt][t] = __builtin_amdgcn_mfma_f32_16x16x32_bf16(ahi[rt], blo, acc[rt][t], 0, 0, 0);
                acc[rt][t] = __builtin_amdgcn_mfma_f32_16x16x32_bf16(alo[rt], bhi, acc[rt][t], 0, 0, 0);
            }
        }
    }
    #pragma unroll
    for (int t = 0; t < NTILE; ++t) {
        float bv = bias[t * 16 + l15];
        #pragma unroll
        for (int rt = 0; rt < 2; ++rt) {
            int rp0 = rbase + rt * 16 + lg * 4;
            #pragma unroll
            for (int r = 0; r < 4; ++r)
                outp[(size_t)(rp0 + r) * XSTRIDE + t * 16 + l15] = acc[rt][t][r] + bv;
        }
    }
}

// ---------------------------------------------------------------------------
// cos/sin table (bit-matches reference fp32 rounding order)
// ---------------------------------------------------------------------------
__global__ void cstab_kernel(float2* __restrict__ tab)
{
    int idx = blockIdx.x * 256 + threadIdx.x;
    if (idx >= TSTEPS * FREQN) return;
    int t = idx / FREQN, j = idx - t * FREQN;
    float time = (float)(t + 1);
    float om = (6.28318530717958647692f * time) * ((float)j / 10.0f);
    float s, c;
    sincosf(om, &s, &c);
    tab[idx] = make_float2(c, s);
}

// ---------------------------------------------------------------------------
// Recurrent kernel R5: block = 2 rows x 8 waves (512 thr), k-split 8/wave.
//  - U regs shared across the 2 rows: per k, 2 readlanes feed 10 FMAs.
//  - wave 0 finalizes row 0 || wave 1 finalizes row 1 (parallel finalize).
//  - cos/sin are wave-uniform scalar loads (depend only on (t,j)).
//  - hsig applied vectorially before per-j readlane.
// ---------------------------------------------------------------------------
__global__ __launch_bounds__(512, 2)
void rec_kernel(const float* __restrict__ xproj,
                const float* __restrict__ Ui, const float* __restrict__ Us,
                const float* __restrict__ Uc, const float* __restrict__ Uo,
                const float* __restrict__ Ufre, const float* __restrict__ Ua,
                const float* __restrict__ ba,
                const float* __restrict__ csTab,   // [t][j][2] = {cos, sin}
                float* __restrict__ state,
                const float* __restrict__ Wp, const float* __restrict__ bp,
                const float* __restrict__ fcw, const float* __restrict__ fcb,
                float* __restrict__ outv,
                int ci, int TC, int nchunks)
{
    __shared__ f32x4 pg[2][8][64];     // 16 KB partials
    __shared__ float pf_[2][8][16];    // 1 KB fre partials
    __shared__ float hlds[2][64];      // h broadcast
    const int tid  = threadIdx.x;
    const int lane = tid & 63, w = tid >> 6;
    const int row0 = blockIdx.x * 2;
    const int myrow = row0 + w;        // valid for w < 2
    const int k0   = w * 8;
    const int jc   = (lane < FREQN) ? lane : (FREQN - 1);

    // per-lane U slice (shared across both rows): 8 x float4 + 8 x float
    float4 Ur[8]; float Uf[8];
    #pragma unroll
    for (int i = 0; i < 8; ++i) {
        int k = k0 + i;
        Ur[i] = make_float4(Ui[k * 64 + lane], Us[k * 64 + lane],
                            Uc[k * 64 + lane], Uo[k * 64 + lane]);
        Uf[i] = Ufre[k * FREQN + jc];
    }

    float hv0, hv1;
    float Sre[FREQN], Sim[FREQN];      // live only in waves 0/1
    if (ci == 0) {
        hv0 = 0.f; hv1 = 0.f;
        #pragma unroll
        for (int j = 0; j < FREQN; ++j) { Sre[j] = 0.f; Sim[j] = 0.f; }
    } else {
        hv0 = state[row0 * 64 + lane];
        hv1 = state[(row0 + 1) * 64 + lane];
        if (w < 2) {
            #pragma unroll
            for (int j = 0; j < FREQN; ++j) {
                Sre[j] = state[65536 + j * 65536 + myrow * 64 + lane];
                Sim[j] = state[65536 + 655360 + j * 65536 + myrow * 64 + lane];
            }
        }
    }

    const float ba_l = ba[lane];
    float sua[FREQN];
    #pragma unroll
    for (int j = 0; j < FREQN; ++j) sua[j] = Ua[j];   // uniform -> SGPR

    // x prefetch (waves 0/1 only, own row)
    const float* xb = xproj + (size_t)myrow * TC * XSTRIDE;
    float xi = 0.f, xs = 0.f, xc = 0.f, xo = 0.f, xf = 0.f;
    if (w < 2) {
        xi = xb[lane]; xs = xb[64 + lane]; xc = xb[128 + lane];
        xo = xb[192 + lane]; xf = xb[256 + jc];
    }

    for (int tt = 0; tt < TC; ++tt) {
        // --- all 8 waves: partial matvec over own 8-k slice, both rows ---
        float a0i = 0.f, a0s = 0.f, a0c = 0.f, a0o = 0.f, a0f = 0.f;
        float a1i = 0.f, a1s = 0.f, a1c = 0.f, a1o = 0.f, a1f = 0.f;
        #pragma unroll
        for (int i = 0; i < 8; ++i) {
            float h0 = rdlane(hv0, k0 + i);
            float h1 = rdlane(hv1, k0 + i);
            a0i = __fmaf_rn(h0, Ur[i].x, a0i);  a1i = __fmaf_rn(h1, Ur[i].x, a1i);
            a0s = __fmaf_rn(h0, Ur[i].y, a0s);  a1s = __fmaf_rn(h1, Ur[i].y, a1s);
            a0c = __fmaf_rn(h0, Ur[i].z, a0c);  a1c = __fmaf_rn(h1, Ur[i].z, a1c);
            a0o = __fmaf_rn(h0, Ur[i].w, a0o);  a1o = __fmaf_rn(h1, Ur[i].w, a1o);
            a0f = __fmaf_rn(h0, Uf[i],  a0f);   a1f = __fmaf_rn(h1, Uf[i],  a1f);
        }
        pg[0][w][lane] = (f32x4){a0i, a0s, a0c, a0o};
        pg[1][w][lane] = (f32x4){a1i, a1s, a1c, a1o};
        if (lane < 16) { pf_[0][w][lane] = a0f; pf_[1][w][lane] = a1f; }
        __syncthreads();

        // --- wave w<2: finalize row (row0+w) ---
        if (w < 2) {
            f32x4 q0 = pg[w][0][lane], q1 = pg[w][1][lane];
            f32x4 q2 = pg[w][2][lane], q3 = pg[w][3][lane];
            f32x4 q4 = pg[w][4][lane], q5 = pg[w][5][lane];
            f32x4 q6 = pg[w][6][lane], q7 = pg[w][7][lane];
            f32x4 qs = ((q0 + q1) + (q2 + q3)) + ((q4 + q5) + (q6 + q7));
            float pfr = ((pf_[w][0][jc] + pf_[w][1][jc]) + (pf_[w][2][jc] + pf_[w][3][jc]))
                      + ((pf_[w][4][jc] + pf_[w][5][jc]) + (pf_[w][6][jc] + pf_[w][7][jc]));
            float cxi = xi, cxs = xs, cxc = xc, cxo = xo, cxf = xf;
            if (tt + 1 < TC) {                    // prefetch next step
                const float* b2 = xb + (size_t)(tt + 1) * XSTRIDE;
                xi = b2[lane]; xs = b2[64 + lane]; xc = b2[128 + lane];
                xo = b2[192 + lane]; xf = b2[256 + jc];
            }
            // wave-uniform cos/sin scalars for this step
            const float* cs = csTab + (size_t)(ci * TC + tt) * (2 * FREQN);
            float gi = hsig(cxi + qs[0]);
            float gs = hsig(cxs + qs[1]);
            float go = hsig(cxo + qs[3]);
            float gc = gi * tanh_f(cxc + qs[2]);
            float freh = hsig(cxf + pfr);          // vector hsig once (lanes 0..9 valid)
            float aacc = 0.f;
            #pragma unroll
            for (int j = 0; j < FREQN; ++j) {
                float fre = rdlane(freh, j);
                float cj = cs[2 * j];              // uniform -> s_load
                float sj = cs[2 * j + 1];
                float fj = gs * fre;
                Sre[j] = __fmaf_rn(fj, Sre[j], gc * cj);
                Sim[j] = __fmaf_rn(fj, Sim[j], gc * sj);
                float Aj = __fmaf_rn(Sre[j], Sre[j], Sim[j] * Sim[j]);
                aacc = __fmaf_rn(Aj, sua[j], aacc);
            }
            hlds[w][lane] = go * tanh_f(aacc + ba_l);
        }
        __syncthreads();
        hv0 = hlds[0][lane];
        hv1 = hlds[1][lane];
    }

    if (ci == nchunks - 1) {
        if (w < 2) {
            float hvm = (w == 0) ? hv0 : hv1;
            float wef = 0.f;
            #pragma unroll
            for (int o = 0; o < NOUT; ++o)
                wef = __fmaf_rn(Wp[lane * NOUT + o], fcw[o], wef);
            float v = hvm * wef;
            #pragma unroll
            for (int off = 32; off > 0; off >>= 1) v += __shfl_xor(v, off, 64);
            if (lane == 0) {
                float cb = fcb[0];
                #pragma unroll
                for (int o = 0; o < NOUT; ++o) cb = __fmaf_rn(bp[o], fcw[o], cb);
                outv[myrow] = v + cb;
            }
        }
    } else if (w < 2) {
        float hvm = (w == 0) ? hv0 : hv1;
        state[myrow * 64 + lane] = hvm;
        #pragma unroll
        for (int j = 0; j < FREQN; ++j) {
            state[65536 + j * 65536 + myrow * 64 + lane] = Sre[j];
            state[65536 + 655360 + j * 65536 + myrow * 64 + lane] = Sim[j];
        }
    }
}

// ---------------------------------------------------------------------------
extern "C" void kernel_launch(void* const* d_in, const int* in_sizes, int n_in,
                              void* d_out, int out_size, void* d_ws, size_t ws_size,
                              hipStream_t stream)
{
    const float* g1  = (const float*)d_in[0];
    const float* Wi  = (const float*)d_in[1];
    const float* Ui  = (const float*)d_in[2];
    const float* bi  = (const float*)d_in[3];
    const float* Wst = (const float*)d_in[4];
    const float* Ust = (const float*)d_in[5];
    const float* bst = (const float*)d_in[6];
    const float* Wfr = (const float*)d_in[7];
    const float* Ufq = (const float*)d_in[8];
    const float* bfr = (const float*)d_in[9];
    const float* Wc  = (const float*)d_in[10];
    const float* Uc  = (const float*)d_in[11];
    const float* bc  = (const float*)d_in[12];
    const float* Wo  = (const float*)d_in[13];
    const float* Uo  = (const float*)d_in[14];
    const float* bo  = (const float*)d_in[15];
    const float* Ua  = (const float*)d_in[16];
    const float* ba  = (const float*)d_in[17];
    const float* Wp  = (const float*)d_in[18];
    const float* bp  = (const float*)d_in[19];
    const float* fcw = (const float*)d_in[20];
    const float* fcb = (const float*)d_in[21];
    float* outv = (float*)d_out;

    const size_t stateFloats = 65536 + 2 * 655360;          // 1,376,256
    const size_t csFloats    = TSTEPS * FREQN * 2;          // 2,560
    const size_t wpkShorts   = (size_t)8 * NTILE * 64 * 16; // 139,264
    int TC = 128;
    while (TC > 8 &&
           ((size_t)1024 * TC * XSTRIDE + stateFloats + csFloats + XSTRIDE) * 4
               + wpkShorts * 2 > ws_size)
        TC >>= 1;
    int tclog = 31 - __builtin_clz((unsigned)TC);
    int nchunks = TSTEPS / TC;

    float*  xproj = (float*)d_ws;
    float*  state = xproj + (size_t)1024 * TC * XSTRIDE;
    float*  csTab = state + stateFloats;
    float*  bias  = csTab + csFloats;
    unsigned short* Wpk = (unsigned short*)(bias + XSTRIDE);

    pack_w<<<36, 256, 0, stream>>>(Wi, Wst, Wc, Wo, Wfr, bi, bst, bc, bo, bfr, Wpk, bias);
    cstab_kernel<<<(TSTEPS * FREQN + 255) / 256, 256, 0, stream>>>((float2*)csTab);

    const int Mt = (1024 * TC) / 128;
    for (int ci = 0; ci < nchunks; ++ci) {
        gemm_mfma<<<Mt, 256, 0, stream>>>(g1, Wpk, bias, xproj, ci, tclog);
        rec_kernel<<<512, 512, 0, stream>>>(xproj, Ui, Ust, Uc, Uo, Ufq, Ua, ba,
                                            csTab, state, Wp, bp, fcw, fcb, outv,
                                            ci, TC, nchunks);
    }
}

// Round 6
// 478.994 us; speedup vs baseline: 1.2816x; 1.2816x over previous
//
#include <hip/hip_runtime.h>
#include <cstdint>

#define TSTEPS  128
#define INDIM   256
#define HIDDEN  64
#define FREQN   10
#define NOUT    16
#define XSTRIDE 272   // xproj cols: [i:0][ste:64][c:128][o:192][fre:256..265][pad..271]
#define NTILE   17    // 272/16 N-tiles

typedef __attribute__((ext_vector_type(8))) short bf16x8;
typedef __attribute__((ext_vector_type(4))) float f32x4;
typedef _Float16 f16;
typedef __attribute__((ext_vector_type(2))) _Float16 f16x2;

__device__ __forceinline__ unsigned short bf16h(float x) {
    unsigned u = __float_as_uint(x);
    return (unsigned short)((u + 0x7FFFu + ((u >> 16) & 1u)) >> 16);
}
__device__ __forceinline__ float rdlane(float v, int l) {
    return __int_as_float(__builtin_amdgcn_readlane(__float_as_int(v), l));
}
__device__ __forceinline__ float hsig(float x) {
    return fminf(fmaxf(__fmaf_rn(x, (1.0f / 6.0f), 0.5f), 0.0f), 1.0f);
}
__device__ __forceinline__ float tanh_f(float x) {
    float e = __expf(2.0f * x);
    return 1.0f - 2.0f / (e + 1.0f);
}
__device__ __forceinline__ float fdot2(f16x2 a, f16x2 b, float c) {
#if __has_builtin(__builtin_amdgcn_fdot2)
    return __builtin_amdgcn_fdot2(a, b, c, false);
#else
    return __fmaf_rn((float)a.x, (float)b.x, __fmaf_rn((float)a.y, (float)b.y, c));
#endif
}

// ---------------------------------------------------------------------------
// Pack W = [Wi|Wst|Wc|Wo|Wfre|0pad] (256 x 272) into split-bf16 MFMA B-frags.
// ---------------------------------------------------------------------------
__global__ void pack_w(const float* __restrict__ Wi, const float* __restrict__ Wst,
                       const float* __restrict__ Wc, const float* __restrict__ Wo,
                       const float* __restrict__ Wfr,
                       const float* __restrict__ bi, const float* __restrict__ bst,
                       const float* __restrict__ bc, const float* __restrict__ bo,
                       const float* __restrict__ bfr,
                       unsigned short* __restrict__ Wpk, float* __restrict__ bias)
{
    int idx = blockIdx.x * 256 + threadIdx.x;
    if (idx < 8 * NTILE * 64) {
        int l = idx & 63;
        int t = (idx >> 6) % NTILE;
        int s = idx / (64 * NTILE);
        int n = t * 16 + (l & 15);
        unsigned short* dst = Wpk + (size_t)idx * 16;
        #pragma unroll
        for (int i = 0; i < 8; ++i) {
            int k = s * 32 + (l >> 4) * 8 + i;
            float v;
            if      (n < 64)  v = Wi [k * 64 + n];
            else if (n < 128) v = Wst[k * 64 + (n - 64)];
            else if (n < 192) v = Wc [k * 64 + (n - 128)];
            else if (n < 256) v = Wo [k * 64 + (n - 192)];
            else if (n < 266) v = Wfr[k * 10 + (n - 256)];
            else              v = 0.f;
            unsigned short h = bf16h(v);
            float hf = __uint_as_float((unsigned)h << 16);
            dst[i]     = h;
            dst[8 + i] = bf16h(v - hf);
        }
    } else if (idx < 8 * NTILE * 64 + XSTRIDE) {
        int n = idx - 8 * NTILE * 64;
        float b;
        if      (n < 64)  b = bi [n];
        else if (n < 128) b = bst[n - 64];
        else if (n < 192) b = bc [n - 128];
        else if (n < 256) b = bo [n - 192];
        else if (n < 266) b = bfr[n - 256];
        else              b = 0.f;
        bias[n] = b;
    }
}

// ---------------------------------------------------------------------------
// Split-bf16 MFMA GEMM: xproj = g1 @ [W...] + bias. (unchanged; ~28 us/chunk)
// ---------------------------------------------------------------------------
__global__ __launch_bounds__(256, 2)
void gemm_mfma(const float* __restrict__ A, const unsigned short* __restrict__ Wpk,
               const float* __restrict__ bias, float* __restrict__ outp,
               int ci, int tclog)
{
    const int tid = threadIdx.x;
    const int w   = tid >> 6, l = tid & 63;
    const int l15 = l & 15,  lg = l >> 4;
    const int tcm = (1 << tclog) - 1;
    const int rbase = blockIdx.x * 128 + w * 32;

    f32x4 acc[2][NTILE];
    #pragma unroll
    for (int rt = 0; rt < 2; ++rt)
        #pragma unroll
        for (int t = 0; t < NTILE; ++t) acc[rt][t] = (f32x4){0.f, 0.f, 0.f, 0.f};

    #pragma unroll
    for (int s = 0; s < 8; ++s) {
        bf16x8 ahi[2], alo[2];
        #pragma unroll
        for (int rt = 0; rt < 2; ++rt) {
            int rp   = rbase + rt * 16 + l15;
            int grow = ((rp >> tclog) << 7) + (ci << tclog) + (rp & tcm);
            const float* ap = A + (size_t)grow * INDIM + s * 32 + lg * 8;
            float4 a0 = *reinterpret_cast<const float4*>(ap);
            float4 a1 = *reinterpret_cast<const float4*>(ap + 4);
            float av[8] = {a0.x, a0.y, a0.z, a0.w, a1.x, a1.y, a1.z, a1.w};
            union { bf16x8 v; unsigned short u[8]; } H, L;
            #pragma unroll
            for (int i = 0; i < 8; ++i) {
                unsigned short h = bf16h(av[i]);
                H.u[i] = h;
                L.u[i] = bf16h(av[i] - __uint_as_float((unsigned)h << 16));
            }
            ahi[rt] = H.v; alo[rt] = L.v;
        }
        #pragma unroll
        for (int t = 0; t < NTILE; ++t) {
            const bf16x8* bp =
                reinterpret_cast<const bf16x8*>(Wpk + ((size_t)(s * NTILE + t) * 64 + l) * 16);
            bf16x8 bhi = bp[0], blo = bp[1];
            #pragma unroll
            for (int rt = 0; rt < 2; ++rt) {
                acc[rt][t] = __builtin_amdgcn_mfma_f32_16x16x32_bf16(ahi[rt], bhi, acc[rt][t], 0, 0, 0);
                acc[rt][t] = __builtin_amdgcn_mfma_f32_16x16x32_bf16(ahi[rt], blo, acc[rt][t], 0, 0, 0);
                acc[rt][t] = __builtin_amdgcn_mfma_f32_16x16x32_bf16(alo[rt], bhi, acc[rt][t], 0, 0, 0);
            }
        }
    }
    #pragma unroll
    for (int t = 0; t < NTILE; ++t) {
        float bv = bias[t * 16 + l15];
        #pragma unroll
        for (int rt = 0; rt < 2; ++rt) {
            int rp0 = rbase + rt * 16 + lg * 4;
            #pragma unroll
            for (int r = 0; r < 4; ++r)
                outp[(size_t)(rp0 + r) * XSTRIDE + t * 16 + l15] = acc[rt][t][r] + bv;
        }
    }
}

// ---------------------------------------------------------------------------
// cos/sin table (bit-matches reference fp32 rounding order)
// ---------------------------------------------------------------------------
__global__ void cstab_kernel(float2* __restrict__ tab)
{
    int idx = blockIdx.x * 256 + threadIdx.x;
    if (idx >= TSTEPS * FREQN) return;
    int t = idx / FREQN, j = idx - t * FREQN;
    float time = (float)(t + 1);
    float om = (6.28318530717958647692f * time) * ((float)j / 10.0f);
    float s, c;
    sincosf(om, &s, &c);
    tab[idx] = make_float2(c, s);
}

// ---------------------------------------------------------------------------
// Recurrent kernel R6: wave = full row, BARRIER-FREE step loop.
//  - U entirely in VGPRs as f16 pairs (160 VGPR), matvec via v_dot2_f32_f16.
//  - h broadcast: pack f16 pairs -> per-wave-private LDS slot -> 8 uniform
//    ds_read_b128 (same-wave ordering, no __syncthreads ever).
//  - no cross-wave exchange, no readlane with runtime base, no idle waves.
// ---------------------------------------------------------------------------
__global__ __launch_bounds__(256, 1)
void rec_kernel(const float* __restrict__ xproj,
                const float* __restrict__ Ui, const float* __restrict__ Us,
                const float* __restrict__ Uc, const float* __restrict__ Uo,
                const float* __restrict__ Ufre, const float* __restrict__ Ua,
                const float* __restrict__ ba,
                const float* __restrict__ csTab,   // [t][j][2] = {cos, sin}
                float* __restrict__ state,
                const float* __restrict__ Wp, const float* __restrict__ bp,
                const float* __restrict__ fcw, const float* __restrict__ fcb,
                float* __restrict__ outv,
                int ci, int TC, int nchunks)
{
    __shared__ __align__(16) unsigned hx[4][32];   // per-wave-private h pairs (f16x2)
    const int tid  = threadIdx.x;
    const int lane = tid & 63, w = tid >> 6;
    const int row  = blockIdx.x * 4 + w;
    const int jc   = (lane < FREQN) ? lane : (FREQN - 1);

    // ---- U -> registers as f16 pairs: Uk[m][g] = {U[2m][lane], U[2m+1][lane]} ----
    f16x2 Uk[32][4];
    f16x2 Uf2[32];
    #pragma unroll
    for (int m = 0; m < 32; ++m) {
        int ka = 2 * m, kb = 2 * m + 1;
        Uk[m][0] = (f16x2){(f16)Ui[ka * 64 + lane], (f16)Ui[kb * 64 + lane]};
        Uk[m][1] = (f16x2){(f16)Us[ka * 64 + lane], (f16)Us[kb * 64 + lane]};
        Uk[m][2] = (f16x2){(f16)Uc[ka * 64 + lane], (f16)Uc[kb * 64 + lane]};
        Uk[m][3] = (f16x2){(f16)Uo[ka * 64 + lane], (f16)Uo[kb * 64 + lane]};
        Uf2[m]   = (f16x2){(f16)Ufre[ka * FREQN + jc], (f16)Ufre[kb * FREQN + jc]};
    }

    float hv;
    float Sre[FREQN], Sim[FREQN];
    if (ci == 0) {
        hv = 0.f;
        #pragma unroll
        for (int j = 0; j < FREQN; ++j) { Sre[j] = 0.f; Sim[j] = 0.f; }
    } else {
        hv = state[row * 64 + lane];
        #pragma unroll
        for (int j = 0; j < FREQN; ++j) {
            Sre[j] = state[65536 + j * 65536 + row * 64 + lane];
            Sim[j] = state[65536 + 655360 + j * 65536 + row * 64 + lane];
        }
    }

    const float ba_l = ba[lane];
    float sua[FREQN];
    #pragma unroll
    for (int j = 0; j < FREQN; ++j) sua[j] = Ua[j];   // uniform -> SGPR

    // publish initial h (f16 pairs) to this wave's LDS slot
    {
        float hb = __shfl_down(hv, 1, 64);
        f16x2 hp; hp.x = (f16)hv; hp.y = (f16)hb;
        if (!(lane & 1)) hx[w][lane >> 1] = __builtin_bit_cast(unsigned, hp);
    }

    const float* xb = xproj + (size_t)row * TC * XSTRIDE;
    float xi = xb[lane], xs = xb[64 + lane], xc = xb[128 + lane];
    float xo = xb[192 + lane], xf = xb[256 + jc];

    for (int tt = 0; tt < TC; ++tt) {
        // uniform-address reads of h pairs (same wave wrote them; lgkmcnt orders)
        unsigned hw_[32];
        #pragma unroll
        for (int m = 0; m < 32; ++m) hw_[m] = hx[w][m];

        float ai = 0.f, as_ = 0.f, ac = 0.f, ao = 0.f, af = 0.f;
        #pragma unroll
        for (int m = 0; m < 32; ++m) {
            f16x2 h2 = __builtin_bit_cast(f16x2, hw_[m]);
            ai  = fdot2(h2, Uk[m][0], ai);
            as_ = fdot2(h2, Uk[m][1], as_);
            ac  = fdot2(h2, Uk[m][2], ac);
            ao  = fdot2(h2, Uk[m][3], ao);
            af  = fdot2(h2, Uf2[m],  af);
        }

        float cxi = xi, cxs = xs, cxc = xc, cxo = xo, cxf = xf;
        if (tt + 1 < TC) {                         // prefetch next step's x
            const float* b2 = xb + (size_t)(tt + 1) * XSTRIDE;
            xi = b2[lane]; xs = b2[64 + lane]; xc = b2[128 + lane];
            xo = b2[192 + lane]; xf = b2[256 + jc];
        }
        const float* cs = csTab + (size_t)(ci * TC + tt) * (2 * FREQN);

        float gi = hsig(cxi + ai);
        float gs = hsig(cxs + as_);
        float go = hsig(cxo + ao);
        float gc = gi * tanh_f(cxc + ac);
        float freh = hsig(cxf + af);               // lanes 0..9 hold fre[j]
        float aacc = 0.f;
        #pragma unroll
        for (int j = 0; j < FREQN; ++j) {
            float fre = rdlane(freh, j);           // literal lane index
            float cj = cs[2 * j];                  // wave-uniform -> s_load
            float sj = cs[2 * j + 1];
            float fj = gs * fre;
            Sre[j] = __fmaf_rn(fj, Sre[j], gc * cj);
            Sim[j] = __fmaf_rn(fj, Sim[j], gc * sj);
            float Aj = __fmaf_rn(Sre[j], Sre[j], Sim[j] * Sim[j]);
            aacc = __fmaf_rn(Aj, sua[j], aacc);
        }
        hv = go * tanh_f(aacc + ba_l);

        // publish h for next step (same wave, no barrier)
        float hb = __shfl_down(hv, 1, 64);
        f16x2 hp; hp.x = (f16)hv; hp.y = (f16)hb;
        if (!(lane & 1)) hx[w][lane >> 1] = __builtin_bit_cast(unsigned, hp);
    }

    if (ci == nchunks - 1) {
        float wef = 0.f;
        #pragma unroll
        for (int o = 0; o < NOUT; ++o)
            wef = __fmaf_rn(Wp[lane * NOUT + o], fcw[o], wef);
        float v = hv * wef;
        #pragma unroll
        for (int off = 32; off > 0; off >>= 1) v += __shfl_xor(v, off, 64);
        if (lane == 0) {
            float cb = fcb[0];
            #pragma unroll
            for (int o = 0; o < NOUT; ++o) cb = __fmaf_rn(bp[o], fcw[o], cb);
            outv[row] = v + cb;
        }
    } else {
        state[row * 64 + lane] = hv;
        #pragma unroll
        for (int j = 0; j < FREQN; ++j) {
            state[65536 + j * 65536 + row * 64 + lane] = Sre[j];
            state[65536 + 655360 + j * 65536 + row * 64 + lane] = Sim[j];
        }
    }
}

// ---------------------------------------------------------------------------
extern "C" void kernel_launch(void* const* d_in, const int* in_sizes, int n_in,
                              void* d_out, int out_size, void* d_ws, size_t ws_size,
                              hipStream_t stream)
{
    const float* g1  = (const float*)d_in[0];
    const float* Wi  = (const float*)d_in[1];
    const float* Ui  = (const float*)d_in[2];
    const float* bi  = (const float*)d_in[3];
    const float* Wst = (const float*)d_in[4];
    const float* Ust = (const float*)d_in[5];
    const float* bst = (const float*)d_in[6];
    const float* Wfr = (const float*)d_in[7];
    const float* Ufq = (const float*)d_in[8];
    const float* bfr = (const float*)d_in[9];
    const float* Wc  = (const float*)d_in[10];
    const float* Uc  = (const float*)d_in[11];
    const float* bc  = (const float*)d_in[12];
    const float* Wo  = (const float*)d_in[13];
    const float* Uo  = (const float*)d_in[14];
    const float* bo  = (const float*)d_in[15];
    const float* Ua  = (const float*)d_in[16];
    const float* ba  = (const float*)d_in[17];
    const float* Wp  = (const float*)d_in[18];
    const float* bp  = (const float*)d_in[19];
    const float* fcw = (const float*)d_in[20];
    const float* fcb = (const float*)d_in[21];
    float* outv = (float*)d_out;

    const size_t stateFloats = 65536 + 2 * 655360;          // 1,376,256
    const size_t csFloats    = TSTEPS * FREQN * 2;          // 2,560
    const size_t wpkShorts   = (size_t)8 * NTILE * 64 * 16; // 139,264
    int TC = 128;
    while (TC > 8 &&
           ((size_t)1024 * TC * XSTRIDE + stateFloats + csFloats + XSTRIDE) * 4
               + wpkShorts * 2 > ws_size)
        TC >>= 1;
    int tclog = 31 - __builtin_clz((unsigned)TC);
    int nchunks = TSTEPS / TC;

    float*  xproj = (float*)d_ws;
    float*  state = xproj + (size_t)1024 * TC * XSTRIDE;
    float*  csTab = state + stateFloats;
    float*  bias  = csTab + csFloats;
    unsigned short* Wpk = (unsigned short*)(bias + XSTRIDE);

    pack_w<<<36, 256, 0, stream>>>(Wi, Wst, Wc, Wo, Wfr, bi, bst, bc, bo, bfr, Wpk, bias);
    cstab_kernel<<<(TSTEPS * FREQN + 255) / 256, 256, 0, stream>>>((float2*)csTab);

    const int Mt = (1024 * TC) / 128;
    for (int ci = 0; ci < nchunks; ++ci) {
        gemm_mfma<<<Mt, 256, 0, stream>>>(g1, Wpk, bias, xproj, ci, tclog);
        rec_kernel<<<256, 256, 0, stream>>>(xproj, Ui, Ust, Uc, Uo, Ufq, Ua, ba,
                                            csTab, state, Wp, bp, fcw, fcb, outv,
                                            ci, TC, nchunks);
    }
}

// Round 7
// 457.485 us; speedup vs baseline: 1.3419x; 1.0470x over previous
//
#include <hip/hip_runtime.h>
#include <cstdint>

#define TSTEPS  128
#define INDIM   256
#define HIDDEN  64
#define FREQN   10
#define NOUT    16
#define XSTRIDE 272   // xproj cols: [i:0][ste:64][c:128][o:192][fre:256..265][pad..271]
#define NTILE   17    // 272/16 N-tiles
#define SLICE   17408 // shorts per s-slice of Wpk (17 tiles * 64 lanes * 16)

typedef __attribute__((ext_vector_type(8))) short bf16x8;
typedef __attribute__((ext_vector_type(8))) unsigned short ushort8;
typedef __attribute__((ext_vector_type(4))) float f32x4;
typedef _Float16 f16;
typedef __attribute__((ext_vector_type(8))) _Float16 f16x8;

__device__ __forceinline__ unsigned short bf16h(float x) {
    unsigned u = __float_as_uint(x);
    return (unsigned short)((u + 0x7FFFu + ((u >> 16) & 1u)) >> 16);
}
__device__ __forceinline__ float rdlane(float v, int l) {
    return __int_as_float(__builtin_amdgcn_readlane(__float_as_int(v), l));
}
__device__ __forceinline__ float hsig(float x) {
    return fminf(fmaxf(__fmaf_rn(x, (1.0f / 6.0f), 0.5f), 0.0f), 1.0f);
}
__device__ __forceinline__ float tanh_f(float x) {
    float e = __expf(2.0f * x);
    return 1.0f - 2.0f / (e + 1.0f);
}
__device__ __forceinline__ unsigned packf16(float a, float b) {
    unsigned short la = __builtin_bit_cast(unsigned short, (f16)a);
    unsigned short lb = __builtin_bit_cast(unsigned short, (f16)b);
    return (unsigned)la | ((unsigned)lb << 16);
}
__device__ __forceinline__ void gload_lds16(const void* g, void* l) {
    __builtin_amdgcn_global_load_lds((const __attribute__((address_space(1))) void*)g,
                                     (__attribute__((address_space(3))) void*)l, 16, 0, 0);
}

// ---------------------------------------------------------------------------
// Pack W = [Wi|Wst|Wc|Wo|Wfre|0pad] (256 x 272) into split-bf16 MFMA B-frags.
// ---------------------------------------------------------------------------
__global__ void pack_w(const float* __restrict__ Wi, const float* __restrict__ Wst,
                       const float* __restrict__ Wc, const float* __restrict__ Wo,
                       const float* __restrict__ Wfr,
                       const float* __restrict__ bi, const float* __restrict__ bst,
                       const float* __restrict__ bc, const float* __restrict__ bo,
                       const float* __restrict__ bfr,
                       unsigned short* __restrict__ Wpk, float* __restrict__ bias)
{
    int idx = blockIdx.x * 256 + threadIdx.x;
    if (idx < 8 * NTILE * 64) {
        int l = idx & 63;
        int t = (idx >> 6) % NTILE;
        int s = idx / (64 * NTILE);
        int n = t * 16 + (l & 15);
        unsigned short* dst = Wpk + (size_t)idx * 16;
        #pragma unroll
        for (int i = 0; i < 8; ++i) {
            int k = s * 32 + (l >> 4) * 8 + i;
            float v;
            if      (n < 64)  v = Wi [k * 64 + n];
            else if (n < 128) v = Wst[k * 64 + (n - 64)];
            else if (n < 192) v = Wc [k * 64 + (n - 128)];
            else if (n < 256) v = Wo [k * 64 + (n - 192)];
            else if (n < 266) v = Wfr[k * 10 + (n - 256)];
            else              v = 0.f;
            unsigned short h = bf16h(v);
            float hf = __uint_as_float((unsigned)h << 16);
            dst[i]     = h;
            dst[8 + i] = bf16h(v - hf);
        }
    } else if (idx < 8 * NTILE * 64 + XSTRIDE) {
        int n = idx - 8 * NTILE * 64;
        float b;
        if      (n < 64)  b = bi [n];
        else if (n < 128) b = bst[n - 64];
        else if (n < 192) b = bc [n - 128];
        else if (n < 256) b = bo [n - 192];
        else if (n < 266) b = bfr[n - 256];
        else              b = 0.f;
        bias[n] = b;
    }
}

// ---------------------------------------------------------------------------
// GEMM v2: B staged in LDS (global_load_lds w16, double-buffered over s).
// Removes the per-wave 272KB global B re-read (R6's latency bottleneck).
// ---------------------------------------------------------------------------
__global__ __launch_bounds__(256, 2)
void gemm_mfma(const float* __restrict__ A, const unsigned short* __restrict__ Wpk,
               const float* __restrict__ bias, float* __restrict__ outp,
               int ci, int tclog)
{
    extern __shared__ short Bsh[];                 // 2 * 17408 shorts = 69632 B
    const int tid = threadIdx.x;
    const int w   = tid >> 6, l = tid & 63;
    const int l15 = l & 15,  lg = l >> 4;
    const int tcm = (1 << tclog) - 1;
    const int rbase = blockIdx.x * 128 + w * 32;

    f32x4 acc[2][NTILE];
    #pragma unroll
    for (int rt = 0; rt < 2; ++rt)
        #pragma unroll
        for (int t = 0; t < NTILE; ++t) acc[rt][t] = (f32x4){0.f, 0.f, 0.f, 0.f};

    // stage s=0 into buf 0 (linear copy: dest = uniform base + lane*16)
    #pragma unroll
    for (int u = 0; u < 9; ++u) {
        int e = u * 256 + tid;                     // 16B-chunk index, 2176 total
        if (e < 2176)
            gload_lds16(Wpk + (size_t)e * 8, &Bsh[e * 8]);
    }
    __syncthreads();                               // drains vmcnt -> buf0 ready

    #pragma unroll
    for (int s = 0; s < 8; ++s) {
        if (s + 1 < 8) {                           // async-stage next slice
            const unsigned short* src = Wpk + (size_t)(s + 1) * SLICE;
            short* dst = &Bsh[((s + 1) & 1) * SLICE];
            #pragma unroll
            for (int u = 0; u < 9; ++u) {
                int e = u * 256 + tid;
                if (e < 2176)
                    gload_lds16(src + (size_t)e * 8, dst + e * 8);
            }
        }
        // A fragments (global, streams from HBM) + split-bf16 conversion
        bf16x8 ahi[2], alo[2];
        #pragma unroll
        for (int rt = 0; rt < 2; ++rt) {
            int rp   = rbase + rt * 16 + l15;
            int grow = ((rp >> tclog) << 7) + (ci << tclog) + (rp & tcm);
            const float* ap = A + (size_t)grow * INDIM + s * 32 + lg * 8;
            float4 a0 = *reinterpret_cast<const float4*>(ap);
            float4 a1 = *reinterpret_cast<const float4*>(ap + 4);
            float av[8] = {a0.x, a0.y, a0.z, a0.w, a1.x, a1.y, a1.z, a1.w};
            union { bf16x8 v; unsigned short u[8]; } H, L;
            #pragma unroll
            for (int i = 0; i < 8; ++i) {
                unsigned short h = bf16h(av[i]);
                H.u[i] = h;
                L.u[i] = bf16h(av[i] - __uint_as_float((unsigned)h << 16));
            }
            ahi[rt] = H.v; alo[rt] = L.v;
        }
        const short* buf = &Bsh[(s & 1) * SLICE];
        #pragma unroll
        for (int t = 0; t < NTILE; ++t) {
            const bf16x8* bp = reinterpret_cast<const bf16x8*>(buf + (t * 64 + l) * 16);
            bf16x8 bhi = bp[0], blo = bp[1];
            #pragma unroll
            for (int rt = 0; rt < 2; ++rt) {
                acc[rt][t] = __builtin_amdgcn_mfma_f32_16x16x32_bf16(ahi[rt], bhi, acc[rt][t], 0, 0, 0);
                acc[rt][t] = __builtin_amdgcn_mfma_f32_16x16x32_bf16(ahi[rt], blo, acc[rt][t], 0, 0, 0);
                acc[rt][t] = __builtin_amdgcn_mfma_f32_16x16x32_bf16(alo[rt], bhi, acc[rt][t], 0, 0, 0);
            }
        }
        __syncthreads();   // staging of s+1 landed; all waves done with buf[s&1]
    }
    // C/D layout (verified): col = lane&15, row = (lane>>4)*4 + reg
    #pragma unroll
    for (int t = 0; t < NTILE; ++t) {
        float bv = bias[t * 16 + l15];
        #pragma unroll
        for (int rt = 0; rt < 2; ++rt) {
            int rp0 = rbase + rt * 16 + lg * 4;
            #pragma unroll
            for (int r = 0; r < 4; ++r)
                outp[(size_t)(rp0 + r) * XSTRIDE + t * 16 + l15] = acc[rt][t][r] + bv;
        }
    }
}

// ---------------------------------------------------------------------------
// cos/sin table (bit-matches reference fp32 rounding order)
// ---------------------------------------------------------------------------
__global__ void cstab_kernel(float2* __restrict__ tab)
{
    int idx = blockIdx.x * 256 + threadIdx.x;
    if (idx >= TSTEPS * FREQN) return;
    int t = idx / FREQN, j = idx - t * FREQN;
    float time = (float)(t + 1);
    float om = (6.28318530717958647692f * time) * ((float)j / 10.0f);
    float s, c;
    sincosf(om, &s, &c);
    tab[idx] = make_float2(c, s);
}

// ---------------------------------------------------------------------------
// Recurrent kernel R7: 1 wave = 1 row; matvec via mfma_f32_16x16x32_f16.
//  - U preloaded as 34 f16x8 B-fragments (136 VGPR); h published to LDS as
//    f16 pairs; A-frag = 2 uniform ds_read_b128; 34 MFMAs/step; D row 0
//    redistributed via LDS. Same-wave LDS ordering -> zero barriers.
//  - A/B/C lane maps identical to the verified gemm_mfma maps.
// ---------------------------------------------------------------------------
__global__ __launch_bounds__(64, 1)
void rec_kernel(const float* __restrict__ xproj,
                const float* __restrict__ Ui, const float* __restrict__ Us,
                const float* __restrict__ Uc, const float* __restrict__ Uo,
                const float* __restrict__ Ufre, const float* __restrict__ Ua,
                const float* __restrict__ ba,
                const float* __restrict__ csTab,   // [t][j][2] = {cos, sin}
                float* __restrict__ state,
                const float* __restrict__ Wp, const float* __restrict__ bp,
                const float* __restrict__ fcw, const float* __restrict__ fcb,
                float* __restrict__ outv,
                int ci, int TC, int nchunks)
{
    __shared__ float rowbuf[XSTRIDE];              // matvec preacts
    __shared__ unsigned h2[32];                    // 64 f16 of h
    const int lane = threadIdx.x;                  // 0..63
    const int row  = blockIdx.x;
    const int l15  = lane & 15, lg = lane >> 4;
    const int jc   = (lane < FREQN) ? lane : (FREQN - 1);

    // ---- preload U into f16 B-fragments: Bf[t][kap], k = kap*32+lg*8+i ----
    f16x8 Bf[NTILE][2];
    #pragma unroll
    for (int t = 0; t < NTILE; ++t) {
        #pragma unroll
        for (int kap = 0; kap < 2; ++kap) {
            union { f16x8 v; f16 e[8]; } u;
            #pragma unroll
            for (int i = 0; i < 8; ++i) {
                int k = kap * 32 + lg * 8 + i;
                int n = t * 16 + l15;
                float v;
                if      (n < 64)  v = Ui [k * 64 + n];
                else if (n < 128) v = Us [k * 64 + (n - 64)];
                else if (n < 192) v = Uc [k * 64 + (n - 128)];
                else if (n < 256) v = Uo [k * 64 + (n - 192)];
                else if (n < 266) v = Ufre[k * 10 + (n - 256)];
                else              v = 0.f;
                u.e[i] = (f16)v;
            }
            Bf[t][kap] = u.v;
        }
    }

    float hv;
    float Sre[FREQN], Sim[FREQN];
    if (ci == 0) {
        hv = 0.f;
        #pragma unroll
        for (int j = 0; j < FREQN; ++j) { Sre[j] = 0.f; Sim[j] = 0.f; }
    } else {
        hv = state[row * 64 + lane];
        #pragma unroll
        for (int j = 0; j < FREQN; ++j) {
            Sre[j] = state[65536 + j * 65536 + row * 64 + lane];
            Sim[j] = state[65536 + 655360 + j * 65536 + row * 64 + lane];
        }
    }

    const float ba_l = ba[lane];
    float sua[FREQN];
    #pragma unroll
    for (int j = 0; j < FREQN; ++j) sua[j] = Ua[j];   // uniform -> SGPR

    // publish initial h as f16 pairs
    {
        float hb = __shfl_down(hv, 1, 64);
        unsigned d = packf16(hv, hb);
        if (!(lane & 1)) h2[lane >> 1] = d;
    }

    const float* xb = xproj + (size_t)row * TC * XSTRIDE;
    float xi = xb[lane], xs = xb[64 + lane], xc = xb[128 + lane];
    float xo = xb[192 + lane], xf = xb[256 + jc];

    for (int tt = 0; tt < TC; ++tt) {
        // A-fragments: uniform 16B reads per lane-group (all rows duplicated)
        f16x8 a0 = *reinterpret_cast<const f16x8*>((const char*)h2 + lg * 16);
        f16x8 a1 = *reinterpret_cast<const f16x8*>((const char*)h2 + 64 + lg * 16);

        #pragma unroll
        for (int t = 0; t < NTILE; ++t) {
            f32x4 z = (f32x4){0.f, 0.f, 0.f, 0.f};
            z = __builtin_amdgcn_mfma_f32_16x16x32_f16(a0, Bf[t][0], z, 0, 0, 0);
            z = __builtin_amdgcn_mfma_f32_16x16x32_f16(a1, Bf[t][1], z, 0, 0, 0);
            if (lane < 16) rowbuf[t * 16 + lane] = z[0];   // D row 0
        }

        float si = rowbuf[lane];
        float ss = rowbuf[64 + lane];
        float sc = rowbuf[128 + lane];
        float so = rowbuf[192 + lane];
        float pfr = rowbuf[256 + jc];

        float cxi = xi, cxs = xs, cxc = xc, cxo = xo, cxf = xf;
        if (tt + 1 < TC) {                         // prefetch next step's x
            const float* b2 = xb + (size_t)(tt + 1) * XSTRIDE;
            xi = b2[lane]; xs = b2[64 + lane]; xc = b2[128 + lane];
            xo = b2[192 + lane]; xf = b2[256 + jc];
        }
        const float* cs = csTab + (size_t)(ci * TC + tt) * (2 * FREQN);

        float gi = hsig(cxi + si);
        float gs = hsig(cxs + ss);
        float go = hsig(cxo + so);
        float gc = gi * tanh_f(cxc + sc);
        float freh = hsig(cxf + pfr);              // lanes 0..9 hold fre[j]
        float aacc = 0.f;
        #pragma unroll
        for (int j = 0; j < FREQN; ++j) {
            float fre = rdlane(freh, j);           // literal lane index
            float cj = cs[2 * j];                  // wave-uniform -> s_load
            float sj = cs[2 * j + 1];
            float fj = gs * fre;
            Sre[j] = __fmaf_rn(fj, Sre[j], gc * cj);
            Sim[j] = __fmaf_rn(fj, Sim[j], gc * sj);
            float Aj = __fmaf_rn(Sre[j], Sre[j], Sim[j] * Sim[j]);
            aacc = __fmaf_rn(Aj, sua[j], aacc);
        }
        hv = go * tanh_f(aacc + ba_l);

        // publish h for next step (same wave, no barrier)
        float hb = __shfl_down(hv, 1, 64);
        unsigned d = packf16(hv, hb);
        if (!(lane & 1)) h2[lane >> 1] = d;
    }

    if (ci == nchunks - 1) {
        float wef = 0.f;
        #pragma unroll
        for (int o = 0; o < NOUT; ++o)
            wef = __fmaf_rn(Wp[lane * NOUT + o], fcw[o], wef);
        float v = hv * wef;
        #pragma unroll
        for (int off = 32; off > 0; off >>= 1) v += __shfl_xor(v, off, 64);
        if (lane == 0) {
            float cb = fcb[0];
            #pragma unroll
            for (int o = 0; o < NOUT; ++o) cb = __fmaf_rn(bp[o], fcw[o], cb);
            outv[row] = v + cb;
        }
    } else {
        state[row * 64 + lane] = hv;
        #pragma unroll
        for (int j = 0; j < FREQN; ++j) {
            state[65536 + j * 65536 + row * 64 + lane] = Sre[j];
            state[65536 + 655360 + j * 65536 + row * 64 + lane] = Sim[j];
        }
    }
}

// ---------------------------------------------------------------------------
extern "C" void kernel_launch(void* const* d_in, const int* in_sizes, int n_in,
                              void* d_out, int out_size, void* d_ws, size_t ws_size,
                              hipStream_t stream)
{
    const float* g1  = (const float*)d_in[0];
    const float* Wi  = (const float*)d_in[1];
    const float* Ui  = (const float*)d_in[2];
    const float* bi  = (const float*)d_in[3];
    const float* Wst = (const float*)d_in[4];
    const float* Ust = (const float*)d_in[5];
    const float* bst = (const float*)d_in[6];
    const float* Wfr = (const float*)d_in[7];
    const float* Ufq = (const float*)d_in[8];
    const float* bfr = (const float*)d_in[9];
    const float* Wc  = (const float*)d_in[10];
    const float* Uc  = (const float*)d_in[11];
    const float* bc  = (const float*)d_in[12];
    const float* Wo  = (const float*)d_in[13];
    const float* Uo  = (const float*)d_in[14];
    const float* bo  = (const float*)d_in[15];
    const float* Ua  = (const float*)d_in[16];
    const float* ba  = (const float*)d_in[17];
    const float* Wp  = (const float*)d_in[18];
    const float* bp  = (const float*)d_in[19];
    const float* fcw = (const float*)d_in[20];
    const float* fcb = (const float*)d_in[21];
    float* outv = (float*)d_out;

    const size_t stateFloats = 65536 + 2 * 655360;          // 1,376,256
    const size_t csFloats    = TSTEPS * FREQN * 2;          // 2,560
    const size_t wpkShorts   = (size_t)8 * NTILE * 64 * 16; // 139,264
    int TC = 128;
    while (TC > 8 &&
           ((size_t)1024 * TC * XSTRIDE + stateFloats + csFloats + XSTRIDE) * 4
               + wpkShorts * 2 > ws_size)
        TC >>= 1;
    int tclog = 31 - __builtin_clz((unsigned)TC);
    int nchunks = TSTEPS / TC;

    float*  xproj = (float*)d_ws;
    float*  state = xproj + (size_t)1024 * TC * XSTRIDE;
    float*  csTab = state + stateFloats;
    float*  bias  = csTab + csFloats;
    unsigned short* Wpk = (unsigned short*)(bias + XSTRIDE);

    hipFuncSetAttribute((const void*)gemm_mfma,
                        hipFuncAttributeMaxDynamicSharedMemorySize, 69632);

    pack_w<<<36, 256, 0, stream>>>(Wi, Wst, Wc, Wo, Wfr, bi, bst, bc, bo, bfr, Wpk, bias);
    cstab_kernel<<<(TSTEPS * FREQN + 255) / 256, 256, 0, stream>>>((float2*)csTab);

    const int Mt = (1024 * TC) / 128;
    for (int ci = 0; ci < nchunks; ++ci) {
        gemm_mfma<<<Mt, 256, 69632, stream>>>(g1, Wpk, bias, xproj, ci, tclog);
        rec_kernel<<<1024, 64, 0, stream>>>(xproj, Ui, Ust, Uc, Uo, Ufq, Ua, ba,
                                            csTab, state, Wp, bp, fcw, fcb, outv,
                                            ci, TC, nchunks);
    }
}